// Round 7
// baseline (55.876 us; speedup 1.0000x reference)
//
#include <hip/hip_runtime.h>

// RefCondMul: x[B=4][64][L=8192] f32, inds[B][L] int32, w[1000][64][64] f32,
// bias[1000][1][64] f32 -> out[B][64][L] f32.
// out[b][o][l] = sum_m x[b][m][l] * w[inds[b][l]][m][o] + bias[inds[b][l]][0][o]
//
// Strategy: class-binning (w read from HBM exactly once: 16 MB vs R4's 183 MB
// measured fabric traffic). R6 lesson: the 41us fills in top-5 are the
// HARNESS's 268MB poison fills (outside timed region); our 46us was really
// the 6-deep serialized kernel chain (two single-block kernels + 5 drain
// boundaries). This round: 3 kernels. Binning prep (hist+scan+scatter) runs
// as ONE extra block inside the transpose kernel, concurrent with the
// transpose blocks.

#define M_DIM 64
#define N_OUTD 64
#define L_DIM 8192
#define B_DIM 4
#define NCLS 1000
#define NSAMP (B_DIM * L_DIM)

typedef float float4v __attribute__((ext_vector_type(4)));
typedef int   int4v   __attribute__((ext_vector_type(4)));

// ---- workspace layout (bytes) ----
#define XT_OFF   0ull            // xt[NSAMP][64] f32 : 8 MB
#define OT_OFF   8388608ull      // ot[NSAMP][64] f32 : 8 MB
#define PERM_OFF 16777216ull     // perm[NSAMP] int   : 128 KB
#define OFFS_OFF 16908288ull     // offs[1001] int
#define WS_NEED  16912392ull

// ============ kernel 1: transpose-in (blocks 0..511) + binprep (block 512) ==
__global__ __launch_bounds__(256) void k_prep(
    const float* __restrict__ x, const int* __restrict__ inds,
    float* __restrict__ xt, int* __restrict__ perm, int* __restrict__ offs) {
  const int tid = threadIdx.x;

  if (blockIdx.x < 512) {
    // ---- transpose tile: xt[n][m] = x[b][m][l], n = b*L+l ----
    __shared__ float tile[64][68];  // [l][m], padded
    const int b  = blockIdx.x >> 7;
    const int l0 = (blockIdx.x & 127) << 6;
    const float* xb = x + ((size_t)b * M_DIM) * L_DIM + l0;
    const int r  = tid >> 4;         // 0..15
    const int c4 = (tid & 15) * 4;   // 0..60
#pragma unroll
    for (int p = 0; p < 4; ++p) {
      const int m = r + 16 * p;
      float4v v = *(const float4v*)(xb + (size_t)m * L_DIM + c4);
#pragma unroll
      for (int q = 0; q < 4; ++q) tile[c4 + q][m] = v[q];
    }
    __syncthreads();
    float* xtb = xt + ((size_t)(b * L_DIM + l0)) * M_DIM;
#pragma unroll
    for (int p = 0; p < 4; ++p) {
      const int li = r + 16 * p;
      float4v v = *(const float4v*)(&tile[li][c4]);
      *(float4v*)(xtb + (size_t)li * M_DIM + c4) = v;   // contiguous
    }
    return;
  }

  // ---- block 512: histogram + scan + scatter, all in one block ----
  __shared__ int h[1024];      // histogram -> (reused) nothing
  __shared__ int cur[1024];    // exclusive offsets -> scatter cursors
  __shared__ int wsum[256];
  const int4v* ip = (const int4v*)inds;   // NSAMP/4 = 8192 int4s

  for (int i = tid; i < 1024; i += 256) h[i] = 0;
  __syncthreads();
  for (int i = tid; i < NSAMP / 4; i += 256) {
    int4v v = ip[i];
    atomicAdd(&h[v.x], 1); atomicAdd(&h[v.y], 1);
    atomicAdd(&h[v.z], 1); atomicAdd(&h[v.w], 1);
  }
  __syncthreads();
  // scan: thread t owns h[4t..4t+3]
  const int a0 = h[4 * tid], a1 = h[4 * tid + 1], a2 = h[4 * tid + 2], a3 = h[4 * tid + 3];
  const int tsum = a0 + a1 + a2 + a3;
  wsum[tid] = tsum;
  __syncthreads();
  for (int off = 1; off < 256; off <<= 1) {
    int t2 = (tid >= off) ? wsum[tid - off] : 0;
    __syncthreads();
    wsum[tid] += t2;
    __syncthreads();
  }
  const int base = wsum[tid] - tsum;   // exclusive over previous threads
  const int e0 = base, e1 = base + a0, e2 = base + a0 + a1, e3 = base + a0 + a1 + a2;
  cur[4 * tid] = e0; cur[4 * tid + 1] = e1; cur[4 * tid + 2] = e2; cur[4 * tid + 3] = e3;
  if (4 * tid     <= NCLS) offs[4 * tid]     = e0;
  if (4 * tid + 1 <= NCLS) offs[4 * tid + 1] = e1;
  if (4 * tid + 2 <= NCLS) offs[4 * tid + 2] = e2;
  if (4 * tid + 3 <= NCLS) offs[4 * tid + 3] = e3;
  __syncthreads();
  // scatter
  for (int i = tid; i < NSAMP / 4; i += 256) {
    int4v v = ip[i];
    const int n0 = i * 4;
    perm[atomicAdd(&cur[v.x], 1)] = n0;
    perm[atomicAdd(&cur[v.y], 1)] = n0 + 1;
    perm[atomicAdd(&cur[v.z], 1)] = n0 + 2;
    perm[atomicAdd(&cur[v.w], 1)] = n0 + 3;
  }
}

// ============ kernel 2: binned matvec, w[c] in LDS ==========================
// grid = 1000 (one block per class). 16 samples/iter; each 16-lane group owns
// one sample, each lane owns 4 outputs. Next iteration's perm/xt gather is
// prefetched into registers during compute (hides ~900cy HBM latency).
__global__ __launch_bounds__(256) void k_main(
    const float* __restrict__ xt, const int* __restrict__ perm,
    const int* __restrict__ offs, const float* __restrict__ w,
    const float* __restrict__ bias, float* __restrict__ ot) {
  __shared__ float wl[4096];        // w[c]: 16 KB
  __shared__ float xs[16][68];      // 16 samples' x, padded rows
  __shared__ int   ns[16];

  const int tid = threadIdx.x;
  const int c   = blockIdx.x;
  const int start = offs[c];
  const int count = offs[c + 1] - start;

  const float* wp = w + (size_t)c * (M_DIM * N_OUTD);
#pragma unroll
  for (int p = 0; p < 4; ++p) {
    const int idx = (p * 256 + tid) * 4;
    *(float4v*)(&wl[idx]) = *(const float4v*)(wp + idx);
  }

  const int wid  = tid >> 6;
  const int lane = tid & 63;
  const int g    = lane >> 4;
  const int oi   = (lane & 15) * 4;
  const int j    = wid * 4 + g;          // compute: sample slot 0..15
  const int sj   = tid >> 4;             // staging: sample slot 0..15
  const int smi  = (tid & 15) * 4;       // staging: m base

  const float4v bv = *(const float4v*)(bias + (size_t)c * N_OUTD + oi);

  // prefetch iteration 0's samples into registers
  int nn = 0; float4v xv = {0.f, 0.f, 0.f, 0.f};
  if (sj < count) {
    nn = perm[start + sj];
    xv = *(const float4v*)(xt + (size_t)nn * M_DIM + smi);
  }
  __syncthreads();  // wl ready

  for (int s0 = 0; s0 < count; s0 += 16) {
    if (s0 + sj < count) {
      *(float4v*)(&xs[sj][smi]) = xv;
      if (smi == 0) ns[sj] = nn;
    }
    __syncthreads();
    // prefetch next 16 samples (overlaps with compute below)
    if (s0 + 16 + sj < count) {
      nn = perm[start + s0 + 16 + sj];
      xv = *(const float4v*)(xt + (size_t)nn * M_DIM + smi);
    }
    if (s0 + j < count) {
      float4v acc = bv;
#pragma unroll
      for (int m = 0; m < M_DIM; ++m) {
        const float4v wv = *(const float4v*)(&wl[m * N_OUTD + oi]);
        acc += xs[j][m] * wv;
      }
      *(float4v*)(ot + (size_t)ns[j] * N_OUTD + oi) = acc;  // 256B/group
    }
    __syncthreads();
  }
}

// ============ kernel 3: transpose-out =======================================
__global__ __launch_bounds__(256) void k_tout(
    const float* __restrict__ ot, float* __restrict__ out) {
  __shared__ float tile[64][68];  // [o][l], padded
  const int tid = threadIdx.x;
  const int b  = blockIdx.x >> 7;
  const int l0 = (blockIdx.x & 127) << 6;

  const float* otb = ot + ((size_t)(b * L_DIM + l0)) * N_OUTD;
  const int r  = tid >> 4;
  const int c4 = (tid & 15) * 4;
#pragma unroll
  for (int p = 0; p < 4; ++p) {
    const int li = r + 16 * p;
    float4v v = *(const float4v*)(otb + (size_t)li * N_OUTD + c4);  // contiguous
#pragma unroll
    for (int q = 0; q < 4; ++q) tile[c4 + q][li] = v[q];
  }
  __syncthreads();
  float* ob = out + ((size_t)b * N_OUTD) * L_DIM + l0;
#pragma unroll
  for (int p = 0; p < 4; ++p) {
    const int o = r + 16 * p;
    float4v v = *(const float4v*)(&tile[o][c4]);
    *(float4v*)(ob + (size_t)o * L_DIM + c4) = v;  // 64B-line writes
  }
}

// ============ fallback (R4 kernel) if ws too small ==========================
#define TL 16
__global__ __launch_bounds__(256) void condmul_fallback(
    const float* __restrict__ x, const int* __restrict__ inds,
    const float* __restrict__ w, const float* __restrict__ bias,
    float* __restrict__ out) {
  __shared__ float xs[M_DIM][TL];
  __shared__ float os[TL][N_OUTD + 4];
  const int tid  = threadIdx.x;
  const int wid  = tid >> 6;
  const int lane = tid & 63;
  const int g    = lane >> 4;
  const int oi   = (lane & 15) * 4;
  const int n0   = blockIdx.x * TL;
  const int b    = n0 / L_DIM;
  const int l0   = n0 % L_DIM;
  {
    const int li = tid & (TL - 1);
    const int m0 = tid >> 4;
    const float* xb = x + ((size_t)b * M_DIM) * L_DIM + l0;
#pragma unroll
    for (int p = 0; p < 4; ++p) {
      const int m = p * 16 + m0;
      xs[m][li] = xb[(size_t)m * L_DIM + li];
    }
  }
  __syncthreads();
  const int li = wid * 4 + g;
  const int c  = inds[n0 + li];
  const float* wp = w + ((size_t)c * M_DIM) * N_OUTD + oi;
  float4v acc = {0.f, 0.f, 0.f, 0.f};
#pragma unroll 8
  for (int m = 0; m < M_DIM; ++m) {
    const float  xv = xs[m][li];
    const float4v wv = *(const float4v*)(wp + (size_t)m * N_OUTD);
    acc += xv * wv;
  }
  acc += *(const float4v*)(bias + (size_t)c * N_OUTD + oi);
  *(float4v*)(&os[li][oi]) = acc;
  __syncthreads();
  {
    const int lo = tid & (TL - 1);
    const int o0 = tid >> 4;
    float* ob = out + ((size_t)b * N_OUTD) * L_DIM + l0;
#pragma unroll
    for (int p = 0; p < 4; ++p) {
      const int o = p * 16 + o0;
      ob[(size_t)o * L_DIM + lo] = os[lo][o];
    }
  }
}

extern "C" void kernel_launch(void* const* d_in, const int* in_sizes, int n_in,
                              void* d_out, int out_size, void* d_ws, size_t ws_size,
                              hipStream_t stream) {
  const float* x    = (const float*)d_in[0];
  const int*   inds = (const int*)d_in[1];
  const float* w    = (const float*)d_in[2];
  const float* bias = (const float*)d_in[3];
  float*       out  = (float*)d_out;

  if (ws_size < WS_NEED) {
    condmul_fallback<<<NSAMP / TL, 256, 0, stream>>>(x, inds, w, bias, out);
    return;
  }

  char* ws = (char*)d_ws;
  float* xt   = (float*)(ws + XT_OFF);
  float* ot   = (float*)(ws + OT_OFF);
  int*   perm = (int*)(ws + PERM_OFF);
  int*   offs = (int*)(ws + OFFS_OFF);

  k_prep<<<513, 256, 0, stream>>>(x, inds, xt, perm, offs);
  k_main<<<NCLS, 256, 0, stream>>>(xt, perm, offs, w, bias, ot);
  k_tout<<<512, 256, 0, stream>>>(ot, out);
}

// Round 8
// 39.470 us; speedup vs baseline: 1.4157x; 1.4157x over previous
//
#include <hip/hip_runtime.h>

// RefCondMul: x[B=4][64][L=8192] f32, inds[B][L] int32, w[1000][64][64] f32,
// bias[1000][1][64] f32 -> out[B][64][L] f32.
// out[b][o][l] = sum_m x[b][m][l] * w[inds[b][l]][m][o] + bias[inds[b][l]][0][o]
//
// Class-binning (w read from HBM exactly once). R7 lesson: single-block
// hist+scan+scatter = 41us (latency-serialized scatter on one CU). R8:
// scatter parallelized across the 512 transpose blocks, which also write x
// rows DIRECTLY into binned layout xg[pos] -> k_main is fully contiguous;
// the (unavoidable) gather moves to k_tout via rank[n].

#define M_DIM 64
#define N_OUTD 64
#define L_DIM 8192
#define B_DIM 4
#define NCLS 1000
#define NSAMP (B_DIM * L_DIM)

typedef float float4v __attribute__((ext_vector_type(4)));
typedef int   int4v   __attribute__((ext_vector_type(4)));

// ---- workspace layout (bytes) ----
#define XG_OFF   0ull            // xg[NSAMP][64] f32, binned order : 8 MB
#define OTB_OFF  8388608ull      // otb[NSAMP][64] f32, binned      : 8 MB
#define RANK_OFF 16777216ull     // rank[NSAMP] int (n -> pos)      : 128 KB
#define OFFS_OFF 16908288ull     // offs[1001] int
#define CUR_OFF  16912384ull     // cur[1000] int (scatter cursors)
#define WS_NEED  16916384ull

// ============ kernel 1: histogram + scan (1 block, 1024 threads) ============
__global__ __launch_bounds__(1024) void k_binprep(
    const int* __restrict__ inds, int* __restrict__ offs, int* __restrict__ cur) {
  __shared__ int h[1024];
  __shared__ int s[1024];
  const int tid = threadIdx.x;
  h[tid] = 0;
  __syncthreads();
  const int4v* ip = (const int4v*)inds;   // NSAMP/4 = 8192 int4s
#pragma unroll
  for (int r = 0; r < NSAMP / 4 / 1024; ++r) {   // 8 int4 per thread
    int4v v = ip[r * 1024 + tid];
    atomicAdd(&h[v.x], 1); atomicAdd(&h[v.y], 1);
    atomicAdd(&h[v.z], 1); atomicAdd(&h[v.w], 1);
  }
  __syncthreads();
  const int v = h[tid];
  s[tid] = v;
  __syncthreads();
  for (int off = 1; off < 1024; off <<= 1) {     // Hillis-Steele inclusive
    int t = (tid >= off) ? s[tid - off] : 0;
    __syncthreads();
    s[tid] += t;
    __syncthreads();
  }
  if (tid < NCLS) {
    const int excl = s[tid] - v;
    offs[tid] = excl;
    cur[tid]  = excl;
  }
  if (tid == NCLS - 1) offs[NCLS] = s[tid];      // total = NSAMP
}

// ============ kernel 2: transpose-in + parallel scatter =====================
// 512 blocks; each owns 64 consecutive l of one b. Claims binned positions
// for its 64 samples via device atomics, writes x columns straight to
// xg[pos][0..63] (256B contiguous per sample) and rank[n]=pos.
__global__ __launch_bounds__(256) void k_tin_scatter(
    const float* __restrict__ x, const int* __restrict__ inds,
    int* __restrict__ cur, float* __restrict__ xg, int* __restrict__ rank) {
  __shared__ float tile[64][68];  // [l][m], padded
  __shared__ int posv[64];
  const int tid = threadIdx.x;
  const int b  = blockIdx.x >> 7;
  const int l0 = (blockIdx.x & 127) << 6;

  if (tid < 64) {
    const int n = b * L_DIM + l0 + tid;
    const int pos = atomicAdd(&cur[inds[n]], 1);
    posv[tid] = pos;
    rank[n] = pos;
  }

  const float* xb = x + ((size_t)b * M_DIM) * L_DIM + l0;
  const int r  = tid >> 4;         // 0..15
  const int c4 = (tid & 15) * 4;   // 0..60
#pragma unroll
  for (int p = 0; p < 4; ++p) {
    const int m = r + 16 * p;
    float4v v = *(const float4v*)(xb + (size_t)m * L_DIM + c4);
#pragma unroll
    for (int q = 0; q < 4; ++q) tile[c4 + q][m] = v[q];
  }
  __syncthreads();
#pragma unroll
  for (int p = 0; p < 4; ++p) {
    const int li = r + 16 * p;
    float4v v = *(const float4v*)(&tile[li][c4]);
    *(float4v*)(xg + (size_t)posv[li] * M_DIM + c4) = v;  // 256B/sample
  }
}

// ============ kernel 3: binned matvec, fully contiguous =====================
// grid = 1000 (one block per class). Samples for class c live at
// xg[offs[c]..offs[c+1]), outputs go to otb same rows. 16 samples/iter;
// each 16-lane group owns one sample, each lane owns 4 outputs. Next
// iteration's x is prefetched into registers during compute.
__global__ __launch_bounds__(256) void k_main(
    const float* __restrict__ xg, const int* __restrict__ offs,
    const float* __restrict__ w, const float* __restrict__ bias,
    float* __restrict__ otb) {
  __shared__ float wl[4096];        // w[c]: 16 KB
  __shared__ float xs[16][68];      // 16 samples' x, padded rows

  const int tid = threadIdx.x;
  const int c   = blockIdx.x;
  const int start = offs[c];
  const int count = offs[c + 1] - start;

  const float* wp = w + (size_t)c * (M_DIM * N_OUTD);
#pragma unroll
  for (int p = 0; p < 4; ++p) {
    const int idx = (p * 256 + tid) * 4;
    *(float4v*)(&wl[idx]) = *(const float4v*)(wp + idx);
  }

  const int wid  = tid >> 6;
  const int lane = tid & 63;
  const int g    = lane >> 4;
  const int oi   = (lane & 15) * 4;
  const int j    = wid * 4 + g;          // compute: sample slot 0..15
  const int sj   = tid >> 4;             // staging: sample slot 0..15
  const int smi  = (tid & 15) * 4;       // staging: m base

  const float4v bv = *(const float4v*)(bias + (size_t)c * N_OUTD + oi);

  // prefetch iteration 0 (contiguous 4KB chunk across the block)
  float4v xv = {0.f, 0.f, 0.f, 0.f};
  if (sj < count) xv = *(const float4v*)(xg + (size_t)(start + sj) * M_DIM + smi);
  __syncthreads();  // wl ready

  for (int s0 = 0; s0 < count; s0 += 16) {
    if (s0 + sj < count) *(float4v*)(&xs[sj][smi]) = xv;
    __syncthreads();
    if (s0 + 16 + sj < count)   // prefetch next 16 samples (overlaps compute)
      xv = *(const float4v*)(xg + (size_t)(start + s0 + 16 + sj) * M_DIM + smi);
    if (s0 + j < count) {
      float4v acc = bv;
#pragma unroll
      for (int m = 0; m < M_DIM; ++m) {
        acc += xs[j][m] * *(const float4v*)(&wl[m * N_OUTD + oi]);
      }
      *(float4v*)(otb + (size_t)(start + s0 + j) * N_OUTD + oi) = acc;  // contiguous
    }
    __syncthreads();
  }
}

// ============ kernel 4: gather + transpose-out ==============================
// out[b][o][l] = otb[rank[b*L+l]][o]; 512 blocks, one 64o x 64l tile.
__global__ __launch_bounds__(256) void k_tout(
    const float* __restrict__ otb, const int* __restrict__ rank,
    float* __restrict__ out) {
  __shared__ float tile[64][68];  // [o][l], padded
  __shared__ int rk[64];
  const int tid = threadIdx.x;
  const int b  = blockIdx.x >> 7;
  const int l0 = (blockIdx.x & 127) << 6;

  if (tid < 64) rk[tid] = rank[b * L_DIM + l0 + tid];
  __syncthreads();

  const int r  = tid >> 4;
  const int c4 = (tid & 15) * 4;
#pragma unroll
  for (int p = 0; p < 4; ++p) {
    const int li = r + 16 * p;
    float4v v = *(const float4v*)(otb + (size_t)rk[li] * N_OUTD + c4);  // 256B/row
#pragma unroll
    for (int q = 0; q < 4; ++q) tile[c4 + q][li] = v[q];
  }
  __syncthreads();
  float* ob = out + ((size_t)b * N_OUTD) * L_DIM + l0;
#pragma unroll
  for (int p = 0; p < 4; ++p) {
    const int o = r + 16 * p;
    float4v v = *(const float4v*)(&tile[o][c4]);
    *(float4v*)(ob + (size_t)o * L_DIM + c4) = v;  // 64B-line writes
  }
}

// ============ fallback (R4 kernel) if ws too small ==========================
#define TL 16
__global__ __launch_bounds__(256) void condmul_fallback(
    const float* __restrict__ x, const int* __restrict__ inds,
    const float* __restrict__ w, const float* __restrict__ bias,
    float* __restrict__ out) {
  __shared__ float xs[M_DIM][TL];
  __shared__ float os[TL][N_OUTD + 4];
  const int tid  = threadIdx.x;
  const int wid  = tid >> 6;
  const int lane = tid & 63;
  const int g    = lane >> 4;
  const int oi   = (lane & 15) * 4;
  const int n0   = blockIdx.x * TL;
  const int b    = n0 / L_DIM;
  const int l0   = n0 % L_DIM;
  {
    const int li = tid & (TL - 1);
    const int m0 = tid >> 4;
    const float* xb = x + ((size_t)b * M_DIM) * L_DIM + l0;
#pragma unroll
    for (int p = 0; p < 4; ++p) {
      const int m = p * 16 + m0;
      xs[m][li] = xb[(size_t)m * L_DIM + li];
    }
  }
  __syncthreads();
  const int li = wid * 4 + g;
  const int c  = inds[n0 + li];
  const float* wp = w + ((size_t)c * M_DIM) * N_OUTD + oi;
  float4v acc = {0.f, 0.f, 0.f, 0.f};
#pragma unroll 8
  for (int m = 0; m < M_DIM; ++m) {
    const float  xv = xs[m][li];
    const float4v wv = *(const float4v*)(wp + (size_t)m * N_OUTD);
    acc += xv * wv;
  }
  acc += *(const float4v*)(bias + (size_t)c * N_OUTD + oi);
  *(float4v*)(&os[li][oi]) = acc;
  __syncthreads();
  {
    const int lo = tid & (TL - 1);
    const int o0 = tid >> 4;
    float* ob = out + ((size_t)b * N_OUTD) * L_DIM + l0;
#pragma unroll
    for (int p = 0; p < 4; ++p) {
      const int o = p * 16 + o0;
      ob[(size_t)o * L_DIM + lo] = os[lo][o];
    }
  }
}

extern "C" void kernel_launch(void* const* d_in, const int* in_sizes, int n_in,
                              void* d_out, int out_size, void* d_ws, size_t ws_size,
                              hipStream_t stream) {
  const float* x    = (const float*)d_in[0];
  const int*   inds = (const int*)d_in[1];
  const float* w    = (const float*)d_in[2];
  const float* bias = (const float*)d_in[3];
  float*       out  = (float*)d_out;

  if (ws_size < WS_NEED) {
    condmul_fallback<<<NSAMP / TL, 256, 0, stream>>>(x, inds, w, bias, out);
    return;
  }

  char* ws = (char*)d_ws;
  float* xg   = (float*)(ws + XG_OFF);
  float* otb  = (float*)(ws + OTB_OFF);
  int*   rank = (int*)(ws + RANK_OFF);
  int*   offs = (int*)(ws + OFFS_OFF);
  int*   cur  = (int*)(ws + CUR_OFF);

  k_binprep<<<1, 1024, 0, stream>>>(inds, offs, cur);
  k_tin_scatter<<<512, 256, 0, stream>>>(x, inds, cur, xg, rank);
  k_main<<<NCLS, 256, 0, stream>>>(xg, offs, w, bias, otb);
  k_tout<<<512, 256, 0, stream>>>(otb, rank, out);
}